// Round 11
// baseline (257.583 us; speedup 1.0000x reference)
//
#include <hip/hip_runtime.h>
#include <cstdint>

#define ALPHA 0.2f

constexpr int NB = 8;
constexpr int NN = 2048;
constexpr int NF = 256;

typedef __attribute__((ext_vector_type(8))) short bf16x8;
typedef __attribute__((ext_vector_type(4))) float f32x4;

__device__ __forceinline__ float bf2f(unsigned short u) {
    union { unsigned int i; float f; } v;
    v.i = ((unsigned int)u) << 16;
    return v.f;
}
__device__ __forceinline__ unsigned short f2bf(float f) {
    union { float f; unsigned int i; } v;
    v.f = f;
    v.i += 0x7fffu + ((v.i >> 16) & 1);  // round-to-nearest-even
    return (unsigned short)(v.i >> 16);
}

// ---------------------------------------------------------------------------
// Kernel 0: WT[f][k] = bf16(W[k][f]) transpose+cast; also zero s1/s2.
// ---------------------------------------------------------------------------
__global__ __launch_bounds__(256) void k_wt(const float* __restrict__ W,
                                            unsigned short* __restrict__ WT,
                                            float* __restrict__ s1,
                                            float* __restrict__ s2) {
    const int t = threadIdx.x;
    const int gid = blockIdx.x * 256 + t;
    s1[gid] = 0.f;
    s2[gid] = 0.f;
    const int k = blockIdx.x * 4 + (t >> 6);
    const int f0 = (t & 63) * 4;
    const float4 w = *(const float4*)&W[k * NF + f0];
    WT[(f0 + 0) * NF + k] = f2bf(w.x);
    WT[(f0 + 1) * NF + k] = f2bf(w.y);
    WT[(f0 + 2) * NF + k] = f2bf(w.z);
    WT[(f0 + 3) * NF + k] = f2bf(w.w);
}

// ---------------------------------------------------------------------------
// Kernel 1: WhT = (h @ W)^T per batch, bf16 MFMA; fused s1/s2 epilogue.
// (unchanged from round 10 — verified)
// ---------------------------------------------------------------------------
__global__ __launch_bounds__(256, 4) void k_wh(const float* __restrict__ h,
                                               const unsigned short* __restrict__ WT,
                                               const float* __restrict__ a,
                                               unsigned short* __restrict__ WhT,
                                               float* __restrict__ s1,
                                               float* __restrict__ s2) {
    __shared__ __align__(16) unsigned short As[64][72];
    __shared__ __align__(16) unsigned short Bs[64][72];
    const int tid = threadIdx.x;
    const int lane = tid & 63;
    const int l16 = lane & 15;
    const int quad = lane >> 4;
    const int wave = tid >> 6;
    const int row0 = (blockIdx.x >> 2) * 64;
    const int col0 = (blockIdx.x & 3) * 64;
    const int bb = row0 >> 11;
    const int n0 = row0 & (NN - 1);
    const int mb = (wave & 1) * 32;
    const int nb = (wave >> 1) * 32;

    f32x4 acc[2][2];
#pragma unroll
    for (int mf = 0; mf < 2; ++mf)
#pragma unroll
        for (int nf = 0; nf < 2; ++nf) acc[mf][nf] = (f32x4){0.f, 0.f, 0.f, 0.f};

    for (int k0 = 0; k0 < NF; k0 += 64) {
#pragma unroll
        for (int it = 0; it < 4; ++it) {
            const int q = tid + it * 256;
            const int r = q >> 4;
            const int k4 = (q & 15) * 4;
            const float4 v = *(const float4*)&h[(size_t)(row0 + r) * NF + k0 + k4];
            ushort4 o;
            o.x = f2bf(v.x); o.y = f2bf(v.y); o.z = f2bf(v.z); o.w = f2bf(v.w);
            *(ushort4*)&As[r][k4] = o;
        }
#pragma unroll
        for (int it = 0; it < 2; ++it) {
            const int q = tid + it * 256;
            const int f = q >> 3;
            const int k8 = (q & 7) * 8;
            *(uint4*)&Bs[f][k8] =
                *(const uint4*)&WT[(size_t)(col0 + f) * NF + k0 + k8];
        }
        __syncthreads();
#pragma unroll
        for (int ks = 0; ks < 64; ks += 32) {
            bf16x8 av[2], bv[2];
#pragma unroll
            for (int mf = 0; mf < 2; ++mf)
                av[mf] = *(const bf16x8*)&As[mb + mf * 16 + l16][ks + quad * 8];
#pragma unroll
            for (int nf = 0; nf < 2; ++nf)
                bv[nf] = *(const bf16x8*)&Bs[nb + nf * 16 + l16][ks + quad * 8];
#pragma unroll
            for (int mf = 0; mf < 2; ++mf)
#pragma unroll
                for (int nf = 0; nf < 2; ++nf)
                    acc[mf][nf] = __builtin_amdgcn_mfma_f32_16x16x32_bf16(
                        av[mf], bv[nf], acc[mf][nf], 0, 0, 0);
        }
        __syncthreads();
    }

#pragma unroll
    for (int mf = 0; mf < 2; ++mf) {
#pragma unroll
        for (int nf = 0; nf < 2; ++nf) {
            const size_t f = col0 + nb + nf * 16 + l16;
            const int nr = n0 + mb + mf * 16 + quad * 4;
            ushort4 o;
            o.x = f2bf(acc[mf][nf][0]);
            o.y = f2bf(acc[mf][nf][1]);
            o.z = f2bf(acc[mf][nf][2]);
            o.w = f2bf(acc[mf][nf][3]);
            *(ushort4*)&WhT[((size_t)bb * NF + f) * NN + nr] = o;
        }
    }

    float a1v[2], a2v[2];
#pragma unroll
    for (int nf = 0; nf < 2; ++nf) {
        const int f = col0 + nb + nf * 16 + l16;
        a1v[nf] = a[f];
        a2v[nf] = a[NF + f];
    }
#pragma unroll
    for (int mf = 0; mf < 2; ++mf) {
#pragma unroll
        for (int r = 0; r < 4; ++r) {
            float p1 = acc[mf][0][r] * a1v[0] + acc[mf][1][r] * a1v[1];
            float p2 = acc[mf][0][r] * a2v[0] + acc[mf][1][r] * a2v[1];
            p1 += __shfl_xor(p1, 1); p2 += __shfl_xor(p2, 1);
            p1 += __shfl_xor(p1, 2); p2 += __shfl_xor(p2, 2);
            p1 += __shfl_xor(p1, 4); p2 += __shfl_xor(p2, 4);
            p1 += __shfl_xor(p1, 8); p2 += __shfl_xor(p2, 8);
            if (l16 == 0) {
                const int n = n0 + mb + mf * 16 + quad * 4 + r;
                atomicAdd(&s1[bb * NN + n], p1);
                atomicAdd(&s2[bb * NN + n], p2);
            }
        }
    }
}

// ---------------------------------------------------------------------------
// Kernel 2: fused masked softmax + attn @ Wh.
// NO WhsT LDS staging: each wave loads its B-fragments straight from global
// (L2-resident WhT) into named bf16x8 regs. Only Pb (P row-major -> A-frag
// transpose) uses LDS (4.9 KB). Software pipeline: adj/s2 prefetched 2 tiles
// ahead (HBM latency), B 1 tile ahead, via unroll-x2 + two named reg sets.
// ---------------------------------------------------------------------------
__global__ __launch_bounds__(256, 3) void k_attn(const unsigned short* __restrict__ WhT,
                                                 const int* __restrict__ adj,
                                                 const float* __restrict__ s1g,
                                                 const float* __restrict__ s2g,
                                                 float* __restrict__ out) {
    __shared__ __align__(16) unsigned short Pb[32][72];  // [i][k] bf16
    __shared__ float s1_s[32];
    __shared__ float l_s[32];

    const int tid = threadIdx.x;
    const int lane = tid & 63;
    const int l16 = lane & 15;
    const int quad = lane >> 4;
    const int wave = tid >> 6;
    const int bb = blockIdx.x >> 6;
    const int i0 = (blockIdx.x & 63) * 32;

    if (tid < 32) {
        s1_s[tid] = s1g[bb * NN + i0 + tid];
        l_s[tid] = 0.f;
    }
    __syncthreads();

    f32x4 acc[2][4];
#pragma unroll
    for (int m = 0; m < 2; ++m)
#pragma unroll
        for (int nf = 0; nf < 4; ++nf) acc[m][nf] = (f32x4){0.f, 0.f, 0.f, 0.f};

    const size_t whtBase = (size_t)bb * NF * NN;
    const size_t adjBase = (size_t)bb * NN * NN;
    const float* s2b = s2g + bb * NN;

    const int pIr = tid >> 4;          // P row-group 0..15
    const int pKq = (tid & 15) * 4;    // 4 consecutive j per thread
    const int* adjP0 = &adj[adjBase + (size_t)(i0 + pIr) * NN + pKq];
    const int* adjP1 = adjP0 + 16 * NN;
    const float* s2P = &s2b[pKq];
    // per-wave B-fragment base: f = wave*64 + l16 (+nf*16), k = quad*8 (+k0)
    const unsigned short* whW = &WhT[whtBase + (size_t)(wave * 64 + l16) * NN + quad * 8];

    bf16x8 w0, w1, w2, w3, w4, w5, w6, w7;   // B frags, current tile
    int4 amA0, amA1, amB0, amB1;             // adj, 2-deep pipeline
    float4 svA, svB;                         // s2,  2-deep pipeline

#define B_LOAD(J0)                                                    \
    do {                                                              \
        const int j_ = (J0);                                          \
        w0 = *(const bf16x8*)&whW[(size_t)(0 * 16) * NN + j_ + 0];    \
        w1 = *(const bf16x8*)&whW[(size_t)(0 * 16) * NN + j_ + 32];   \
        w2 = *(const bf16x8*)&whW[(size_t)(1 * 16) * NN + j_ + 0];    \
        w3 = *(const bf16x8*)&whW[(size_t)(1 * 16) * NN + j_ + 32];   \
        w4 = *(const bf16x8*)&whW[(size_t)(2 * 16) * NN + j_ + 0];    \
        w5 = *(const bf16x8*)&whW[(size_t)(2 * 16) * NN + j_ + 32];   \
        w6 = *(const bf16x8*)&whW[(size_t)(3 * 16) * NN + j_ + 0];    \
        w7 = *(const bf16x8*)&whW[(size_t)(3 * 16) * NN + j_ + 32];   \
    } while (0)

#define ADJ_LOAD(AM0, AM1, SV, J0)                                    \
    do {                                                              \
        const int j_ = (J0);                                          \
        AM0 = *(const int4*)&adjP0[j_];                               \
        AM1 = *(const int4*)&adjP1[j_];                               \
        SV = *(const float4*)&s2P[j_];                                \
    } while (0)

#define P_HALF(AV, SV, IR)                                            \
    do {                                                              \
        const float s1v = s1_s[IR];                                   \
        float x0 = s1v + SV.x, x1 = s1v + SV.y;                       \
        float x2 = s1v + SV.z, x3 = s1v + SV.w;                       \
        x0 = x0 > 0.f ? x0 : ALPHA * x0;                              \
        x1 = x1 > 0.f ? x1 : ALPHA * x1;                              \
        x2 = x2 > 0.f ? x2 : ALPHA * x2;                              \
        x3 = x3 > 0.f ? x3 : ALPHA * x3;                              \
        const float p0 = AV.x > 0 ? __expf(x0) : 0.f;                 \
        const float p1 = AV.y > 0 ? __expf(x1) : 0.f;                 \
        const float p2 = AV.z > 0 ? __expf(x2) : 0.f;                 \
        const float p3 = AV.w > 0 ? __expf(x3) : 0.f;                 \
        uint2 pk;                                                     \
        pk.x = (unsigned int)f2bf(p0) | ((unsigned int)f2bf(p1) << 16);\
        pk.y = (unsigned int)f2bf(p2) | ((unsigned int)f2bf(p3) << 16);\
        *(uint2*)&Pb[IR][pKq] = pk;                                   \
        float ps = (p0 + p1) + (p2 + p3);                             \
        ps += __shfl_xor(ps, 8);                                      \
        ps += __shfl_xor(ps, 4);                                      \
        ps += __shfl_xor(ps, 2);                                      \
        ps += __shfl_xor(ps, 1);                                      \
        if ((tid & 15) == 0) l_s[IR] += ps;                           \
    } while (0)

#define MFMA_PHASE()                                                  \
    do {                                                              \
        bf16x8 af0 = *(const bf16x8*)&Pb[l16][quad * 8];              \
        bf16x8 af1 = *(const bf16x8*)&Pb[16 + l16][quad * 8];         \
        acc[0][0] = __builtin_amdgcn_mfma_f32_16x16x32_bf16(af0, w0, acc[0][0], 0, 0, 0); \
        acc[1][0] = __builtin_amdgcn_mfma_f32_16x16x32_bf16(af1, w0, acc[1][0], 0, 0, 0); \
        acc[0][1] = __builtin_amdgcn_mfma_f32_16x16x32_bf16(af0, w2, acc[0][1], 0, 0, 0); \
        acc[1][1] = __builtin_amdgcn_mfma_f32_16x16x32_bf16(af1, w2, acc[1][1], 0, 0, 0); \
        acc[0][2] = __builtin_amdgcn_mfma_f32_16x16x32_bf16(af0, w4, acc[0][2], 0, 0, 0); \
        acc[1][2] = __builtin_amdgcn_mfma_f32_16x16x32_bf16(af1, w4, acc[1][2], 0, 0, 0); \
        acc[0][3] = __builtin_amdgcn_mfma_f32_16x16x32_bf16(af0, w6, acc[0][3], 0, 0, 0); \
        acc[1][3] = __builtin_amdgcn_mfma_f32_16x16x32_bf16(af1, w6, acc[1][3], 0, 0, 0); \
        af0 = *(const bf16x8*)&Pb[l16][32 + quad * 8];                \
        af1 = *(const bf16x8*)&Pb[16 + l16][32 + quad * 8];           \
        acc[0][0] = __builtin_amdgcn_mfma_f32_16x16x32_bf16(af0, w1, acc[0][0], 0, 0, 0); \
        acc[1][0] = __builtin_amdgcn_mfma_f32_16x16x32_bf16(af1, w1, acc[1][0], 0, 0, 0); \
        acc[0][1] = __builtin_amdgcn_mfma_f32_16x16x32_bf16(af0, w3, acc[0][1], 0, 0, 0); \
        acc[1][1] = __builtin_amdgcn_mfma_f32_16x16x32_bf16(af1, w3, acc[1][1], 0, 0, 0); \
        acc[0][2] = __builtin_amdgcn_mfma_f32_16x16x32_bf16(af0, w5, acc[0][2], 0, 0, 0); \
        acc[1][2] = __builtin_amdgcn_mfma_f32_16x16x32_bf16(af1, w5, acc[1][2], 0, 0, 0); \
        acc[0][3] = __builtin_amdgcn_mfma_f32_16x16x32_bf16(af0, w7, acc[0][3], 0, 0, 0); \
        acc[1][3] = __builtin_amdgcn_mfma_f32_16x16x32_bf16(af1, w7, acc[1][3], 0, 0, 0); \
    } while (0)

    constexpr int NT = NN / 64;  // 32 tiles
    ADJ_LOAD(amA0, amA1, svA, 0);
    ADJ_LOAD(amB0, amB1, svB, 64);
    B_LOAD(0);

    for (int t = 0; t < NT; t += 2) {
        // ---- tile t (even) : adj set A ----
        P_HALF(amA0, svA, pIr);
        P_HALF(amA1, svA, pIr + 16);
        __syncthreads();
        MFMA_PHASE();
        B_LOAD((t + 1) * 64);  // t+1 < NT (NT even)
        {
            const int j2 = (t + 2 < NT) ? (t + 2) * 64 : 0;
            ADJ_LOAD(amA0, amA1, svA, j2);
        }
        __syncthreads();
        // ---- tile t+1 (odd) : adj set B ----
        P_HALF(amB0, svB, pIr);
        P_HALF(amB1, svB, pIr + 16);
        __syncthreads();
        MFMA_PHASE();
        {
            const int j1 = (t + 2 < NT) ? (t + 2) * 64 : 0;
            B_LOAD(j1);
        }
        {
            const int j3 = (t + 3 < NT) ? (t + 3) * 64 : 0;
            ADJ_LOAD(amB0, amB1, svB, j3);
        }
        __syncthreads();
    }
#undef B_LOAD
#undef ADJ_LOAD
#undef P_HALF
#undef MFMA_PHASE

    // ---- epilogue ----
    if (tid < 32) l_s[tid] = 1.0f / l_s[tid];
    __syncthreads();

    const int f0 = wave * 64;
#pragma unroll
    for (int m = 0; m < 2; ++m) {
#pragma unroll
        for (int r = 0; r < 4; ++r) {
            const int row = m * 16 + quad * 4 + r;
            const float inv = l_s[row];
#pragma unroll
            for (int nf = 0; nf < 4; ++nf) {
                out[((size_t)bb * NN + i0 + row) * NF + f0 + nf * 16 + l16] =
                    acc[m][nf][r] * inv;
            }
        }
    }
}

// ---------------------------------------------------------------------------
extern "C" void kernel_launch(void* const* d_in, const int* in_sizes, int n_in,
                              void* d_out, int out_size, void* d_ws, size_t ws_size,
                              hipStream_t stream) {
    const float* h = (const float*)d_in[0];
    const int* adj = (const int*)d_in[1];
    const float* W = (const float*)d_in[2];
    const float* a = (const float*)d_in[3];
    float* out = (float*)d_out;

    unsigned short* WhT = (unsigned short*)d_ws;  // 8.4 MB bf16, [b][f][n]
    float* s1 = (float*)((char*)d_ws + (size_t)NB * NN * NF * sizeof(unsigned short));
    float* s2 = s1 + (size_t)NB * NN;
    unsigned short* WT = (unsigned short*)(s2 + (size_t)NB * NN);  // 128 KB

    k_wt<<<dim3(64), dim3(256), 0, stream>>>(W, WT, s1, s2);
    k_wh<<<dim3((NB * NN / 64) * (NF / 64)), dim3(256), 0, stream>>>(h, WT, a, WhT, s1, s2);
    k_attn<<<dim3(NB * (NN / 32)), dim3(256), 0, stream>>>(WhT, adj, s1, s2, out);
}

// Round 12
// 254.018 us; speedup vs baseline: 1.0140x; 1.0140x over previous
//
#include <hip/hip_runtime.h>
#include <cstdint>

#define ALPHA 0.2f

constexpr int NB = 8;
constexpr int NN = 2048;
constexpr int NF = 256;

typedef __attribute__((ext_vector_type(8))) short bf16x8;
typedef __attribute__((ext_vector_type(4))) float f32x4;

__device__ __forceinline__ float bf2f(unsigned short u) {
    union { unsigned int i; float f; } v;
    v.i = ((unsigned int)u) << 16;
    return v.f;
}
__device__ __forceinline__ unsigned short f2bf(float f) {
    union { float f; unsigned int i; } v;
    v.f = f;
    v.i += 0x7fffu + ((v.i >> 16) & 1);  // round-to-nearest-even
    return (unsigned short)(v.i >> 16);
}

// Barrier WITHOUT vmcnt drain: orders LDS (lgkmcnt) only; in-flight global
// prefetches keep flying across it. __syncthreads() would drain vmcnt(0).
#define WBAR() asm volatile("s_waitcnt lgkmcnt(0)\n\ts_barrier" ::: "memory")

// ---------------------------------------------------------------------------
// Kernel 0: WT[f][k] = bf16(W[k][f]) transpose+cast; also zero s1/s2.
// ---------------------------------------------------------------------------
__global__ __launch_bounds__(256) void k_wt(const float* __restrict__ W,
                                            unsigned short* __restrict__ WT,
                                            float* __restrict__ s1,
                                            float* __restrict__ s2) {
    const int t = threadIdx.x;
    const int gid = blockIdx.x * 256 + t;
    s1[gid] = 0.f;
    s2[gid] = 0.f;
    const int k = blockIdx.x * 4 + (t >> 6);
    const int f0 = (t & 63) * 4;
    const float4 w = *(const float4*)&W[k * NF + f0];
    WT[(f0 + 0) * NF + k] = f2bf(w.x);
    WT[(f0 + 1) * NF + k] = f2bf(w.y);
    WT[(f0 + 2) * NF + k] = f2bf(w.z);
    WT[(f0 + 3) * NF + k] = f2bf(w.w);
}

// ---------------------------------------------------------------------------
// Kernel 1: WhT = (h @ W)^T per batch, bf16 MFMA; fused s1/s2 epilogue.
// (verified green rounds 10/11 — unchanged)
// ---------------------------------------------------------------------------
__global__ __launch_bounds__(256, 4) void k_wh(const float* __restrict__ h,
                                               const unsigned short* __restrict__ WT,
                                               const float* __restrict__ a,
                                               unsigned short* __restrict__ WhT,
                                               float* __restrict__ s1,
                                               float* __restrict__ s2) {
    __shared__ __align__(16) unsigned short As[64][72];
    __shared__ __align__(16) unsigned short Bs[64][72];
    const int tid = threadIdx.x;
    const int lane = tid & 63;
    const int l16 = lane & 15;
    const int quad = lane >> 4;
    const int wave = tid >> 6;
    const int row0 = (blockIdx.x >> 2) * 64;
    const int col0 = (blockIdx.x & 3) * 64;
    const int bb = row0 >> 11;
    const int n0 = row0 & (NN - 1);
    const int mb = (wave & 1) * 32;
    const int nb = (wave >> 1) * 32;

    f32x4 acc[2][2];
#pragma unroll
    for (int mf = 0; mf < 2; ++mf)
#pragma unroll
        for (int nf = 0; nf < 2; ++nf) acc[mf][nf] = (f32x4){0.f, 0.f, 0.f, 0.f};

    for (int k0 = 0; k0 < NF; k0 += 64) {
#pragma unroll
        for (int it = 0; it < 4; ++it) {
            const int q = tid + it * 256;
            const int r = q >> 4;
            const int k4 = (q & 15) * 4;
            const float4 v = *(const float4*)&h[(size_t)(row0 + r) * NF + k0 + k4];
            ushort4 o;
            o.x = f2bf(v.x); o.y = f2bf(v.y); o.z = f2bf(v.z); o.w = f2bf(v.w);
            *(ushort4*)&As[r][k4] = o;
        }
#pragma unroll
        for (int it = 0; it < 2; ++it) {
            const int q = tid + it * 256;
            const int f = q >> 3;
            const int k8 = (q & 7) * 8;
            *(uint4*)&Bs[f][k8] =
                *(const uint4*)&WT[(size_t)(col0 + f) * NF + k0 + k8];
        }
        __syncthreads();
#pragma unroll
        for (int ks = 0; ks < 64; ks += 32) {
            bf16x8 av[2], bv[2];
#pragma unroll
            for (int mf = 0; mf < 2; ++mf)
                av[mf] = *(const bf16x8*)&As[mb + mf * 16 + l16][ks + quad * 8];
#pragma unroll
            for (int nf = 0; nf < 2; ++nf)
                bv[nf] = *(const bf16x8*)&Bs[nb + nf * 16 + l16][ks + quad * 8];
#pragma unroll
            for (int mf = 0; mf < 2; ++mf)
#pragma unroll
                for (int nf = 0; nf < 2; ++nf)
                    acc[mf][nf] = __builtin_amdgcn_mfma_f32_16x16x32_bf16(
                        av[mf], bv[nf], acc[mf][nf], 0, 0, 0);
        }
        __syncthreads();
    }

#pragma unroll
    for (int mf = 0; mf < 2; ++mf) {
#pragma unroll
        for (int nf = 0; nf < 2; ++nf) {
            const size_t f = col0 + nb + nf * 16 + l16;
            const int nr = n0 + mb + mf * 16 + quad * 4;
            ushort4 o;
            o.x = f2bf(acc[mf][nf][0]);
            o.y = f2bf(acc[mf][nf][1]);
            o.z = f2bf(acc[mf][nf][2]);
            o.w = f2bf(acc[mf][nf][3]);
            *(ushort4*)&WhT[((size_t)bb * NF + f) * NN + nr] = o;
        }
    }

    float a1v[2], a2v[2];
#pragma unroll
    for (int nf = 0; nf < 2; ++nf) {
        const int f = col0 + nb + nf * 16 + l16;
        a1v[nf] = a[f];
        a2v[nf] = a[NF + f];
    }
#pragma unroll
    for (int mf = 0; mf < 2; ++mf) {
#pragma unroll
        for (int r = 0; r < 4; ++r) {
            float p1 = acc[mf][0][r] * a1v[0] + acc[mf][1][r] * a1v[1];
            float p2 = acc[mf][0][r] * a2v[0] + acc[mf][1][r] * a2v[1];
            p1 += __shfl_xor(p1, 1); p2 += __shfl_xor(p2, 1);
            p1 += __shfl_xor(p1, 2); p2 += __shfl_xor(p2, 2);
            p1 += __shfl_xor(p1, 4); p2 += __shfl_xor(p2, 4);
            p1 += __shfl_xor(p1, 8); p2 += __shfl_xor(p2, 8);
            if (l16 == 0) {
                const int n = n0 + mb + mf * 16 + quad * 4 + r;
                atomicAdd(&s1[bb * NN + n], p1);
                atomicAdd(&s2[bb * NN + n], p2);
            }
        }
    }
}

// ---------------------------------------------------------------------------
// Kernel 2: fused masked softmax + attn @ Wh.
// B-frags direct from global (L2-resident WhT), double-buffered reg sets.
// Pb double-buffered in LDS -> ONE raw barrier per tile, never draining vmcnt.
// adj/s2 prefetched 2 tiles ahead; l-sum in per-thread regs (no in-loop LDS).
// ---------------------------------------------------------------------------
__global__ __launch_bounds__(256, 2) void k_attn(const unsigned short* __restrict__ WhT,
                                                 const int* __restrict__ adj,
                                                 const float* __restrict__ s1g,
                                                 const float* __restrict__ s2g,
                                                 float* __restrict__ out) {
    __shared__ __align__(16) unsigned short PbA[32][72];  // [i][k] bf16
    __shared__ __align__(16) unsigned short PbB[32][72];
    __shared__ float l_s[32];

    const int tid = threadIdx.x;
    const int lane = tid & 63;
    const int l16 = lane & 15;
    const int quad = lane >> 4;
    const int wave = tid >> 6;
    const int bb = blockIdx.x >> 6;
    const int i0 = (blockIdx.x & 63) * 32;

    f32x4 acc[2][4];
#pragma unroll
    for (int m = 0; m < 2; ++m)
#pragma unroll
        for (int nf = 0; nf < 4; ++nf) acc[m][nf] = (f32x4){0.f, 0.f, 0.f, 0.f};

    const size_t whtBase = (size_t)bb * NF * NN;
    const size_t adjBase = (size_t)bb * NN * NN;
    const float* s2b = s2g + bb * NN;

    const int pIr = tid >> 4;          // P row 0..15 (half 2: +16)
    const int pKq = (tid & 15) * 4;    // 4 consecutive j per thread
    const int* adjP0 = &adj[adjBase + (size_t)(i0 + pIr) * NN + pKq];
    const int* adjP1 = adjP0 + 16 * NN;
    const float* s2P = &s2b[pKq];
    const unsigned short* whW = &WhT[whtBase + (size_t)(wave * 64 + l16) * NN + quad * 8];

    const float s1v0 = s1g[bb * NN + i0 + pIr];
    const float s1v1 = s1g[bb * NN + i0 + 16 + pIr];
    float lacc0 = 0.f, lacc1 = 0.f;

    // double-buffered B fragments (named scalars -> guaranteed VGPRs)
    bf16x8 wa0, wa1, wa2, wa3, wa4, wa5, wa6, wa7;
    bf16x8 wb0, wb1, wb2, wb3, wb4, wb5, wb6, wb7;
    int4 amA0, amA1, amB0, amB1;
    float4 svA, svB;

#define B_LOAD(P, J0)                                                  \
    do {                                                               \
        const int j_ = (J0);                                           \
        P##0 = *(const bf16x8*)&whW[(size_t)(0 * 16) * NN + j_ + 0];   \
        P##1 = *(const bf16x8*)&whW[(size_t)(0 * 16) * NN + j_ + 32];  \
        P##2 = *(const bf16x8*)&whW[(size_t)(1 * 16) * NN + j_ + 0];   \
        P##3 = *(const bf16x8*)&whW[(size_t)(1 * 16) * NN + j_ + 32];  \
        P##4 = *(const bf16x8*)&whW[(size_t)(2 * 16) * NN + j_ + 0];   \
        P##5 = *(const bf16x8*)&whW[(size_t)(2 * 16) * NN + j_ + 32];  \
        P##6 = *(const bf16x8*)&whW[(size_t)(3 * 16) * NN + j_ + 0];   \
        P##7 = *(const bf16x8*)&whW[(size_t)(3 * 16) * NN + j_ + 32];  \
    } while (0)

#define ADJ_LOAD(AM0, AM1, SV, J0)                                     \
    do {                                                               \
        const int j_ = (J0);                                           \
        AM0 = *(const int4*)&adjP0[j_];                                \
        AM1 = *(const int4*)&adjP1[j_];                                \
        SV = *(const float4*)&s2P[j_];                                 \
    } while (0)

#define P_HALF(AV, SV, S1V, IR, PB, LACC)                              \
    do {                                                               \
        float x0 = (S1V) + SV.x, x1 = (S1V) + SV.y;                    \
        float x2 = (S1V) + SV.z, x3 = (S1V) + SV.w;                    \
        x0 = x0 > 0.f ? x0 : ALPHA * x0;                               \
        x1 = x1 > 0.f ? x1 : ALPHA * x1;                               \
        x2 = x2 > 0.f ? x2 : ALPHA * x2;                               \
        x3 = x3 > 0.f ? x3 : ALPHA * x3;                               \
        const float p0 = AV.x > 0 ? __expf(x0) : 0.f;                  \
        const float p1 = AV.y > 0 ? __expf(x1) : 0.f;                  \
        const float p2 = AV.z > 0 ? __expf(x2) : 0.f;                  \
        const float p3 = AV.w > 0 ? __expf(x3) : 0.f;                  \
        uint2 pk;                                                      \
        pk.x = (unsigned int)f2bf(p0) | ((unsigned int)f2bf(p1) << 16);\
        pk.y = (unsigned int)f2bf(p2) | ((unsigned int)f2bf(p3) << 16);\
        *(uint2*)&PB[IR][pKq] = pk;                                    \
        LACC += (p0 + p1) + (p2 + p3);                                 \
    } while (0)

#define MFMA_PHASE(PB, W)                                              \
    do {                                                               \
        bf16x8 af0 = *(const bf16x8*)&PB[l16][quad * 8];               \
        bf16x8 af1 = *(const bf16x8*)&PB[16 + l16][quad * 8];          \
        acc[0][0] = __builtin_amdgcn_mfma_f32_16x16x32_bf16(af0, W##0, acc[0][0], 0, 0, 0); \
        acc[1][0] = __builtin_amdgcn_mfma_f32_16x16x32_bf16(af1, W##0, acc[1][0], 0, 0, 0); \
        acc[0][1] = __builtin_amdgcn_mfma_f32_16x16x32_bf16(af0, W##2, acc[0][1], 0, 0, 0); \
        acc[1][1] = __builtin_amdgcn_mfma_f32_16x16x32_bf16(af1, W##2, acc[1][1], 0, 0, 0); \
        acc[0][2] = __builtin_amdgcn_mfma_f32_16x16x32_bf16(af0, W##4, acc[0][2], 0, 0, 0); \
        acc[1][2] = __builtin_amdgcn_mfma_f32_16x16x32_bf16(af1, W##4, acc[1][2], 0, 0, 0); \
        acc[0][3] = __builtin_amdgcn_mfma_f32_16x16x32_bf16(af0, W##6, acc[0][3], 0, 0, 0); \
        acc[1][3] = __builtin_amdgcn_mfma_f32_16x16x32_bf16(af1, W##6, acc[1][3], 0, 0, 0); \
        af0 = *(const bf16x8*)&PB[l16][32 + quad * 8];                 \
        af1 = *(const bf16x8*)&PB[16 + l16][32 + quad * 8];            \
        acc[0][0] = __builtin_amdgcn_mfma_f32_16x16x32_bf16(af0, W##1, acc[0][0], 0, 0, 0); \
        acc[1][0] = __builtin_amdgcn_mfma_f32_16x16x32_bf16(af1, W##1, acc[1][0], 0, 0, 0); \
        acc[0][1] = __builtin_amdgcn_mfma_f32_16x16x32_bf16(af0, W##3, acc[0][1], 0, 0, 0); \
        acc[1][1] = __builtin_amdgcn_mfma_f32_16x16x32_bf16(af1, W##3, acc[1][1], 0, 0, 0); \
        acc[0][2] = __builtin_amdgcn_mfma_f32_16x16x32_bf16(af0, W##5, acc[0][2], 0, 0, 0); \
        acc[1][2] = __builtin_amdgcn_mfma_f32_16x16x32_bf16(af1, W##5, acc[1][2], 0, 0, 0); \
        acc[0][3] = __builtin_amdgcn_mfma_f32_16x16x32_bf16(af0, W##7, acc[0][3], 0, 0, 0); \
        acc[1][3] = __builtin_amdgcn_mfma_f32_16x16x32_bf16(af1, W##7, acc[1][3], 0, 0, 0); \
    } while (0)

    constexpr int NT = NN / 64;  // 32 tiles
    ADJ_LOAD(amA0, amA1, svA, 0);
    ADJ_LOAD(amB0, amB1, svB, 64);
    B_LOAD(wa, 0);

    for (int t = 0; t < NT; t += 2) {
        // ---- even tile t ----
        B_LOAD(wb, (t + 1) * 64);  // next tile's B, flies through P+barrier
        P_HALF(amA0, svA, s1v0, pIr, PbA, lacc0);
        P_HALF(amA1, svA, s1v1, pIr + 16, PbA, lacc1);
        {
            const int j2 = (t + 2 < NT) ? (t + 2) * 64 : 0;
            ADJ_LOAD(amA0, amA1, svA, j2);
        }
        WBAR();  // publish PbA; vmcnt NOT drained
        MFMA_PHASE(PbA, wa);
        // ---- odd tile t+1 ----
        {
            const int j2 = (t + 2 < NT) ? (t + 2) * 64 : 0;
            B_LOAD(wa, j2);
        }
        P_HALF(amB0, svB, s1v0, pIr, PbB, lacc0);
        P_HALF(amB1, svB, s1v1, pIr + 16, PbB, lacc1);
        {
            const int j3 = (t + 3 < NT) ? (t + 3) * 64 : 0;
            ADJ_LOAD(amB0, amB1, svB, j3);
        }
        WBAR();  // publish PbB
        MFMA_PHASE(PbB, wb);
    }
#undef B_LOAD
#undef ADJ_LOAD
#undef P_HALF
#undef MFMA_PHASE

    // ---- l reduction: 16 threads share each row ----
    lacc0 += __shfl_xor(lacc0, 1); lacc1 += __shfl_xor(lacc1, 1);
    lacc0 += __shfl_xor(lacc0, 2); lacc1 += __shfl_xor(lacc1, 2);
    lacc0 += __shfl_xor(lacc0, 4); lacc1 += __shfl_xor(lacc1, 4);
    lacc0 += __shfl_xor(lacc0, 8); lacc1 += __shfl_xor(lacc1, 8);
    if ((tid & 15) == 0) {
        l_s[pIr] = lacc0;
        l_s[pIr + 16] = lacc1;
    }
    __syncthreads();
    if (tid < 32) l_s[tid] = 1.0f / l_s[tid];
    __syncthreads();

    const int f0 = wave * 64;
#pragma unroll
    for (int m = 0; m < 2; ++m) {
#pragma unroll
        for (int r = 0; r < 4; ++r) {
            const int row = m * 16 + quad * 4 + r;
            const float inv = l_s[row];
#pragma unroll
            for (int nf = 0; nf < 4; ++nf) {
                out[((size_t)bb * NN + i0 + row) * NF + f0 + nf * 16 + l16] =
                    acc[m][nf][r] * inv;
            }
        }
    }
}

// ---------------------------------------------------------------------------
extern "C" void kernel_launch(void* const* d_in, const int* in_sizes, int n_in,
                              void* d_out, int out_size, void* d_ws, size_t ws_size,
                              hipStream_t stream) {
    const float* h = (const float*)d_in[0];
    const int* adj = (const int*)d_in[1];
    const float* W = (const float*)d_in[2];
    const float* a = (const float*)d_in[3];
    float* out = (float*)d_out;

    unsigned short* WhT = (unsigned short*)d_ws;  // 8.4 MB bf16, [b][f][n]
    float* s1 = (float*)((char*)d_ws + (size_t)NB * NN * NF * sizeof(unsigned short));
    float* s2 = s1 + (size_t)NB * NN;
    unsigned short* WT = (unsigned short*)(s2 + (size_t)NB * NN);  // 128 KB

    k_wt<<<dim3(64), dim3(256), 0, stream>>>(W, WT, s1, s2);
    k_wh<<<dim3((NB * NN / 64) * (NF / 64)), dim3(256), 0, stream>>>(h, WT, a, WhT, s1, s2);
    k_attn<<<dim3(NB * (NN / 32)), dim3(256), 0, stream>>>(WhT, adj, s1, s2, out);
}